// Round 8
// baseline (159.866 us; speedup 1.0000x reference)
//
#include <hip/hip_runtime.h>

// y = q_tok(x) @ q_grp(W)^T + bias, factored exactly:
//   q(x) = g_x * s_x[m], q(W) = g_w * s_w[n,grp] (grp=128 along K)
//   y[m,n] = s_x[m] * sum_grp s_w[n,grp] * (sum_{k in grp} g_x g_w)
// R13: B-operand direct-to-register from global (wq is L2-resident),
// bypassing LDS on the B side. Wave decomposition 1m x 4n (wave tile
// 128x32) so each wave owns a DISJOINT 32-row B slice -- no duplicate
// loads. Direct load = exact bytes of the old LDS path (bit-identical).
// A stays on the verified gld16+LDS+swizzle path (now reused 4x).
// Per iter: {2 gld16 A(g+1), 2 loads B(g+1)} -> vmcnt(4) -> B1 ->
// 8 ds_read A + 2 sv -> lgkm(0) -> B2 -> 16 MFMA (setprio). LDS 32 KB.
// Quant unchanged.

#define M_TOK 2048
#define N_OUT 4096
#define K_IN  4096
#define KB    2048    // packed fp4 bytes per K row (K_IN/2)
#define KSTR  (16 * KB)   // byte stride between B fragment rows (ni step)
#define XBLK  2048    // x-role: one block per token row
#define WBLK  8192    // w-role: 2048 floats (16 groups) per block

typedef __attribute__((ext_vector_type(4))) int   int4v;
typedef __attribute__((ext_vector_type(8))) int   int8v;
typedef __attribute__((ext_vector_type(4))) float floatx4;

// fp4-e2m1 nibble via scale-premultiplied decision thresholds
// T = {.25,.75,1.25,1.75,2.5,3.5,5}*scale; codes 0..7 = {0,.5,1,1.5,2,3,4,6}
__device__ __forceinline__ unsigned int q_nib(
    float v, float t0, float t1, float t2, float t3, float t4, float t5, float t6)
{
    float a = fabsf(v);
    unsigned int m =
        a < t0 ? 0u : a < t1 ? 1u : a < t2 ? 2u : a < t3 ? 3u :
        a < t4 ? 4u : a < t5 ? 5u : a < t6 ? 6u : 7u;
    return m | ((__float_as_uint(v) >> 28) & 0x8u);
}

#define MK_THR(scale) \
    const float t0 = 0.25f * (scale), t1 = 0.75f * (scale), \
                t2 = 1.25f * (scale), t3 = 1.75f * (scale), \
                t4 = 2.5f  * (scale), t5 = 3.5f  * (scale), \
                t6 = 5.0f  * (scale);

// ---------- fused quant: blocks [0,XBLK) per-token x, rest per-group w ----------
__global__ __launch_bounds__(256) void quant_fused_kernel(
    const float* __restrict__ x, const float* __restrict__ w,
    unsigned char* __restrict__ xq, float* __restrict__ sx,
    unsigned char* __restrict__ wq, float* __restrict__ swt)
{
    const int t = threadIdx.x;
    const int lane = t & 63, wid = t >> 6;

    if (blockIdx.x < XBLK) {
        // ---- per-token row of 4096: clamp [-3,3], scale = absmax/6 ----
        // coalesced: phase i loads float4 at i*1024 + t*4 (16B/lane contiguous)
        const int row = blockIdx.x;
        const float* xr = x + (size_t)row * K_IN;
        float4 v[4];
        float amax = 0.0f;
        #pragma unroll
        for (int i = 0; i < 4; i++) {
            float4 a = *(const float4*)(xr + i * 1024 + t * 4);
            a.x = fminf(fmaxf(a.x, -3.0f), 3.0f);
            a.y = fminf(fmaxf(a.y, -3.0f), 3.0f);
            a.z = fminf(fmaxf(a.z, -3.0f), 3.0f);
            a.w = fminf(fmaxf(a.w, -3.0f), 3.0f);
            v[i] = a;
            amax = fmaxf(amax, fmaxf(fmaxf(fabsf(a.x), fabsf(a.y)),
                                     fmaxf(fabsf(a.z), fabsf(a.w))));
        }
        #pragma unroll
        for (int off = 32; off; off >>= 1)
            amax = fmaxf(amax, __shfl_xor(amax, off));
        __shared__ float smax[4];
        if (lane == 0) smax[wid] = amax;
        __syncthreads();
        amax = fmaxf(fmaxf(smax[0], smax[1]), fmaxf(smax[2], smax[3]));

        const float scale = amax / 6.0f;
        if (t == 0) sx[row] = scale;
        MK_THR(scale);
        unsigned char* xo = xq + (size_t)row * KB;
        #pragma unroll
        for (int i = 0; i < 4; i++) {
            unsigned int u = q_nib(v[i].x, t0,t1,t2,t3,t4,t5,t6)
                           | (q_nib(v[i].y, t0,t1,t2,t3,t4,t5,t6) << 4)
                           | (q_nib(v[i].z, t0,t1,t2,t3,t4,t5,t6) << 8)
                           | (q_nib(v[i].w, t0,t1,t2,t3,t4,t5,t6) << 12);
            *(unsigned short*)(xo + i * 512 + t * 2) = (unsigned short)u;
        }
    } else {
        // ---- per-group w: block = 2048 floats = 16 groups; 16 lanes/group,
        //      8 consecutive elements per lane -> one packed uint ----
        const int b = blockIdx.x - XBLK;
        const float* base = w + (size_t)b * 2048 + t * 8;
        float4 v0 = *(const float4*)base;
        float4 v1 = *(const float4*)(base + 4);
        float vals[8] = {v0.x, v0.y, v0.z, v0.w, v1.x, v1.y, v1.z, v1.w};
        float amax = 0.0f;
        #pragma unroll
        for (int j = 0; j < 8; j++) amax = fmaxf(amax, fabsf(vals[j]));
        #pragma unroll
        for (int off = 4; off; off >>= 1)   // reduce within 16-lane cluster
            amax = fmaxf(amax, __shfl_xor(amax, off));
        amax = fmaxf(amax, __shfl_xor(amax, 8));
        const float scale = amax / 6.0f;
        const int G = b * 16 + (t >> 4);    // flat group id = n*32 + gk
        if ((lane & 15) == 0) swt[(size_t)(G & 31) * N_OUT + (G >> 5)] = scale;
        MK_THR(scale);
        unsigned int u = 0;
        #pragma unroll
        for (int j = 0; j < 8; j++)
            u |= q_nib(vals[j], t0,t1,t2,t3,t4,t5,t6) << (4 * j);
        *(unsigned int*)(wq + (size_t)b * 1024 + t * 4) = u;
    }
}

// ---------- async 16B global->LDS ----------
__device__ __forceinline__ void gld16(const unsigned char* g, unsigned char* l) {
    __builtin_amdgcn_global_load_lds(
        (const __attribute__((address_space(1))) void*)g,
        (__attribute__((address_space(3))) void*)l, 16, 0, 0);
}

// fragment read with the 8-row-period swizzle (verified 0-conflict, R9/R11)
__device__ __forceinline__ int4v frag4(const unsigned char* buf, int row, int lq) {
    const int slot = (lq + (row >> 1)) & 3;
    return *(const int4v*)&buf[row * 64 + slot * 16];
}
__device__ __forceinline__ int8v ext8(int4v d) {
    return (int8v){d[0], d[1], d[2], d[3], 0, 0, 0, 0};
}

// ---------- MX-fp4 GEMM, BK=128 = one quant group per MFMA ----------
// Tile 128x128, 4 waves (1m x 4n), wave tile 128x32. A via LDS (gld16 +
// swizzle, reused 4x), B direct-to-register (disjoint 32 rows per wave).
__global__ __launch_bounds__(256, 2) void gemm_mx4_kernel(
    const unsigned char* __restrict__ A, const float* __restrict__ sx,
    const unsigned char* __restrict__ B, const float* __restrict__ swt,
    const float* __restrict__ bias, float* __restrict__ C)
{
    __shared__ __align__(16) unsigned char As[2][128 * 64];  // 16 KB
    __shared__ __align__(16) float svs[32][128];             // 16 KB

    const int tid = threadIdx.x;
    const int m0 = blockIdx.y * 128;
    const int n0 = blockIdx.x * 128;
    const int lane = tid & 63;
    const int wid  = tid >> 6;
    const int wn = wid * 32;         // wave n-offset: 0/32/64/96 (disjoint)
    const int lr = lane & 15;
    const int lq = lane >> 4;

    floatx4 mast[8][2] = {};

    // A staging: swizzle phys-slot = (c + (row>>1)) & 3; inverse on the
    // global source so the LDS dest stays wave-uniform + lane*16.
    // 512 chunks(16B) per slot -> 2/thread.
    const unsigned char* gA[2];
    int ldst[2];
    #pragma unroll
    for (int i = 0; i < 2; i++) {
        const int P = tid + i * 256;
        const int row = P >> 2, ph = P & 3;
        const int c = (ph - (row >> 1)) & 3;     // logical chunk at phys ph
        gA[i] = A + (size_t)(m0 + row) * KB + c * 16;
        ldst[i] = P * 16;
    }

    // B direct-load base: fragment (ni, g) at gBr + ni*KSTR + g*64.
    // Exact bytes of the old LDS path: row (n0+wn+ni*16+lr), k-slab lq.
    const unsigned char* gBr = B + (size_t)(n0 + wn + lr) * KB + lq * 16;

#define STAGE_A(gg, ss) do {                                   \
        const int koff_ = (gg) * 64;                           \
        gld16(gA[0] + koff_, &As[ss][ldst[0]]);                \
        gld16(gA[1] + koff_, &As[ss][ldst[1]]);                \
    } while (0)

    // one-time stage of this block's weight scales: swt[g][n0..n0+128)
    // (issued before STAGE_A so their auto-waits don't drain gld16s)
    {
        float4 tmp[4];
        #pragma unroll
        for (int i = 0; i < 4; i++) {
            const int flat = tid + i * 256;      // float4 index, 1024 total
            const int g = flat >> 5, c = (flat & 31) << 2;
            tmp[i] = *(const float4*)(swt + (size_t)g * N_OUT + n0 + c);
        }
        #pragma unroll
        for (int i = 0; i < 4; i++) {
            const int flat = tid + i * 256;
            const int g = flat >> 5, c = (flat & 31) << 2;
            *(float4*)&svs[g][c] = tmp[i];
        }
    }
    // prologue: stage k-group 0 (A into slot 0, B into register set A)
    STAGE_A(0, 0);
    int4v brA0, brA1, brB0, brB1;
    brA0 = *(const int4v*)(gBr);
    brA1 = *(const int4v*)(gBr + KSTR);
    asm volatile("s_waitcnt lgkmcnt(0)" ::: "memory");  // svs ds_writes done

    const floatx4 zero = {0.0f, 0.0f, 0.0f, 0.0f};

    // Per iter: prefetch {A(g+1) 2 gld16, B(g+1) 2 loads} -> vmcnt(4)
    // (A(g)+B(g) complete) -> B1 publish -> 8 ds_read A + 2 sv -> lgkm(0)
    // -> B2 release -> 16 MFMA. Named B-register sets alternate (static).
#define BODY(G, S, BC0, BC1, BN0, BN1, PF) do {                              \
        if (PF) {                                                            \
            STAGE_A((G) + 1, (S) ^ 1);                                       \
            BN0 = *(const int4v*)(gBr + ((G) + 1) * 64);                     \
            BN1 = *(const int4v*)(gBr + KSTR + ((G) + 1) * 64);              \
            asm volatile("s_waitcnt vmcnt(4)" ::: "memory");                 \
        } else {                                                             \
            asm volatile("s_waitcnt vmcnt(0)" ::: "memory");                 \
        }                                                                    \
        __builtin_amdgcn_s_barrier();            /* B1: As[S] published */   \
        __builtin_amdgcn_sched_barrier(0);                                   \
        const float sv0 = svs[G][wn + lr];                                   \
        const float sv1 = svs[G][wn + 16 + lr];                              \
        int4v af[8];                                                         \
        _Pragma("unroll")                                                    \
        for (int mi = 0; mi < 8; mi++)                                       \
            af[mi] = frag4(As[S], mi * 16 + lr, lq);                         \
        asm volatile("s_waitcnt lgkmcnt(0)" ::: "memory");                   \
        __builtin_amdgcn_sched_barrier(0);       /* rule #18 */              \
        __builtin_amdgcn_s_barrier();            /* B2: As[S] free */        \
        __builtin_amdgcn_s_setprio(1);                                       \
        _Pragma("unroll")                                                    \
        for (int mi = 0; mi < 8; mi++) {                                     \
            floatx4 t0_ = __builtin_amdgcn_mfma_scale_f32_16x16x128_f8f6f4(  \
                ext8(af[mi]), ext8(BC0), zero, 4, 4,                         \
                0, 0x7F7F7F7F, 0, 0x7F7F7F7F);                               \
            mast[mi][0] += sv0 * t0_;                                        \
            floatx4 t1_ = __builtin_amdgcn_mfma_scale_f32_16x16x128_f8f6f4(  \
                ext8(af[mi]), ext8(BC1), zero, 4, 4,                         \
                0, 0x7F7F7F7F, 0, 0x7F7F7F7F);                               \
            mast[mi][1] += sv1 * t1_;                                        \
        }                                                                    \
        __builtin_amdgcn_s_setprio(0);                                       \
    } while (0)

    #pragma unroll 1
    for (int g = 0; g < 30; g += 2) {
        BODY(g,     0, brA0, brA1, brB0, brB1, 1);
        BODY(g + 1, 1, brB0, brB1, brA0, brA1, 1);
    }
    BODY(30, 0, brA0, brA1, brB0, brB1, 1);
    BODY(31, 1, brB0, brB1, brA0, brA1, 0);
#undef BODY
#undef STAGE_A

    // epilogue: C/D layout col=lane&15, row=(lane>>4)*4+reg [m89/m91]
    #pragma unroll
    for (int mi = 0; mi < 8; mi++) {
        const int rbase = m0 + mi * 16 + lq * 4;
        #pragma unroll
        for (int ni = 0; ni < 2; ni++) {
            const int cc = n0 + wn + ni * 16 + lr;
            const float bb = bias[cc];
            #pragma unroll
            for (int r = 0; r < 4; r++)
                C[(size_t)(rbase + r) * N_OUT + cc] =
                    sx[rbase + r] * mast[mi][ni][r] + bb;
        }
    }
}

extern "C" void kernel_launch(void* const* d_in, const int* in_sizes, int n_in,
                              void* d_out, int out_size, void* d_ws, size_t ws_size,
                              hipStream_t stream) {
    const float* x    = (const float*)d_in[0];
    const float* w    = (const float*)d_in[1];
    const float* bias = (const float*)d_in[2];
    float* out = (float*)d_out;

    unsigned char* xq = (unsigned char*)d_ws;                       // 4 MB
    unsigned char* wq = xq + (size_t)M_TOK * KB;                    // 8 MB
    float* swt = (float*)(wq + (size_t)N_OUT * KB);                 // 512 KB, [32][4096]
    float* sx  = swt + (size_t)(K_IN / 128) * N_OUT;                // 8 KB

    quant_fused_kernel<<<XBLK + WBLK, 256, 0, stream>>>(x, w, xq, sx, wq, swt);
    gemm_mx4_kernel<<<dim3(N_OUT / 128, M_TOK / 128), 256, 0, stream>>>(
        xq, sx, wq, swt, bias, out);
}